// Round 9
// baseline (986.397 us; speedup 1.0000x reference)
//
#include <hip/hip_runtime.h>
#include <math.h>

#define NN    8192      // nodes
#define PP    3         // meta-paths
#define INF_  256       // input features
#define HID_  64
#define HEADS 8
#define OUTF  64
#define NE    262144    // edges per path (2^18)
#define HD    512       // HEADS*HID
#define DEGCAP 128      // multinomial(262144,8192): mean 32, max ~70; 128 is 16 sigma

typedef __attribute__((ext_vector_type(8))) short short8;
typedef __attribute__((ext_vector_type(4))) float f32x4;

// round-to-nearest-even fp32 -> bf16
__device__ __forceinline__ unsigned short f2bf(float f) {
    unsigned u = __float_as_uint(f);
    unsigned r = u + 0x7fffu + ((u >> 16) & 1u);
    return (unsigned short)(r >> 16);
}
__device__ __forceinline__ float bf2f_lo(unsigned v) { return __uint_as_float(v << 16); }
__device__ __forceinline__ float bf2f_hi(unsigned v) { return __uint_as_float(v & 0xffff0000u); }

// beta from wsum bins (identical fp32 sequence in every consumer kernel)
__device__ __forceinline__ void beta_from_wsum(
        const float* __restrict__ wsum, float* __restrict__ shb) {
    int tid = threadIdx.x;
    if (tid < 64) {
        float s0 = wsum[tid], s1 = wsum[64 + tid], s2 = wsum[128 + tid];
#pragma unroll
        for (int off = 32; off > 0; off >>= 1) {
            s0 += __shfl_down(s0, off);
            s1 += __shfl_down(s1, off);
            s2 += __shfl_down(s2, off);
        }
        if (tid == 0) {
            float w0 = s0 / (float)NN, w1 = s1 / (float)NN, w2 = s2 / (float)NN;
            float m  = fmaxf(w0, fmaxf(w1, w2));
            float e0 = expf(w0 - m), e1 = expf(w1 - m), e2 = expf(w2 - m);
            float ss = e0 + e1 + e2;
            shb[0] = e0 / ss; shb[1] = e1 / ss; shb[2] = e2 / ss;
        }
    }
    __syncthreads();
}

// ---- K0: casts (blocks 0..3583) + LDS-histogram counts (blocks 3584..3599) ----
__global__ __launch_bounds__(256) void cast_count(
        const float* __restrict__ h, const float* __restrict__ fc,
        const int* __restrict__ esrc, const int* __restrict__ edst,
        unsigned short* __restrict__ hb, unsigned short* __restrict__ fcT,
        int* __restrict__ counts /* [4][NN] */) {
    __shared__ int hbin[NN];   // 32 KB, used by histogram blocks only
    int b = blockIdx.x, t = threadIdx.x;
    if (b < 2048) {                               // h: 2M elems, float4
        int i = b * 256 + t;
        float4 v = *(const float4*)(h + (size_t)i * 4);
        ushort4 o = { f2bf(v.x), f2bf(v.y), f2bf(v.z), f2bf(v.w) };
        *(ushort4*)(hb + (size_t)i * 4) = o;
    } else if (b < 2048 + 1536) {                 // fc: 393216 elems, transpose
        int i = (b - 2048) * 256 + t;
        if (i < PP * INF_ * HD) {
            int p = i / (INF_ * HD);
            int rem = i - p * INF_ * HD;
            int k = rem / HD;
            int n = rem - k * HD;
            fcT[(size_t)p * HD * INF_ + (size_t)n * INF_ + k] = f2bf(fc[i]);
        }
    } else {                                      // 16 histogram blocks
        for (int j = t; j < NN; j += 256) hbin[j] = 0;
        __syncthreads();
        int hb_ = b - 3584;
        if (hb_ < 12) {                           // dst histogram: 4 chunks per p
            int p = hb_ >> 2, chunk = hb_ & 3;
            const int* e = edst + (size_t)p * NE + chunk * 65536;
            for (int j = t; j < 65536; j += 256) atomicAdd(&hbin[e[j]], 1);
            __syncthreads();
            for (int j = t; j < NN; j += 256) {
                int c = hbin[j];
                if (c) atomicAdd(&counts[p * NN + j], c);
            }
        } else {                                  // src histogram: 4 chunks over all p
            int chunk = hb_ - 12;
            const int* e = esrc + (size_t)chunk * 196608;
            for (int j = t; j < 196608; j += 256) atomicAdd(&hbin[e[j]], 1);
            __syncthreads();
            for (int j = t; j < NN; j += 256) {
                int c = hbin[j];
                if (c) atomicAdd(&counts[3 * NN + j], c);
            }
        }
    }
}

// ---- K1: exclusive scans (blocks 0..3) + collapsed semantic vec (block 4) ----
__global__ __launch_bounds__(1024) void scan_vw(
        const int* __restrict__ counts, int* __restrict__ offsets,
        int* __restrict__ cursor, const float* __restrict__ w1,
        const float* __restrict__ b1, const float* __restrict__ w2,
        float* __restrict__ v /* [513] */) {
    int t = threadIdx.x;
    if (blockIdx.x == 4) {
        if (t < HD) {
            float s = 0.f;
            for (int k = 0; k < 128; ++k) s += w1[t * 128 + k] * w2[k];
            v[t] = s;
        } else if (t == HD) {
            float c = 0.f;
            for (int k = 0; k < 128; ++k) c += b1[k] * w2[k];
            v[HD] = c;
        }
        return;
    }
    __shared__ int sh[1024];
    int seg = blockIdx.x;
    const int* cnt = counts + seg * NN;
    int* offs = offsets + seg * (NN + 1);
    int* cur  = cursor + seg * NN;
    int loc[8];
    int s = 0;
#pragma unroll
    for (int i = 0; i < 8; ++i) { loc[i] = cnt[t * 8 + i]; s += loc[i]; }
    sh[t] = s;
    __syncthreads();
    for (int off = 1; off < 1024; off <<= 1) {
        int vv = (t >= off) ? sh[t - off] : 0;
        __syncthreads();
        sh[t] += vv;
        __syncthreads();
    }
    int run = sh[t] - s;
#pragma unroll
    for (int i = 0; i < 8; ++i) {
        offs[t * 8 + i] = run;
        cur[t * 8 + i]  = run;
        run += loc[i];
    }
    if (t == 1023) offs[NN] = run;
}

// ---- K2: scatter — dst-CSR stores SRC VALUES; src-CSR stores (alpha-pos, dst) ----
__global__ __launch_bounds__(256) void scatter_all(
        const int* __restrict__ esrc, const int* __restrict__ edst,
        int* __restrict__ cursor, int* __restrict__ ssrc_sorted,
        int* __restrict__ ssorted, int* __restrict__ sdst) {
    int i = blockIdx.x * blockDim.x + threadIdx.x;
    if (i >= PP * NE) return;
    int p = i >> 18;
    int s = esrc[i], d = edst[i];
    int pos = atomicAdd(&cursor[p * NN + d], 1);
    ssrc_sorted[(size_t)p * NE + pos] = s;     // src value directly
    int pos2 = atomicAdd(&cursor[3 * NN + s], 1);
    ssorted[pos2] = p * NE + pos;              // alpha position (dst-sorted)
    sdst[pos2]    = d;
}

// ---- K3: feat[p] = h @ fc_p  via bf16 MFMA; bf16 feat out + fused el/er ----
#define LDK 56   // padded LDS row stride (bf16): 112B rows, 16B-aligned
__global__ __launch_bounds__(256) void gemm_feat_mfma(
        const unsigned short* __restrict__ hb,   // [NN, INF_] bf16
        const unsigned short* __restrict__ fcT,  // [PP, HD, INF_] bf16
        const float* __restrict__ al_all,        // [PP, HD]
        const float* __restrict__ ar_all,        // [PP, HD]
        unsigned short* __restrict__ featb,      // [PP, NN, HD] bf16
        float* __restrict__ el,                  // [PP, NN, HEADS]
        float* __restrict__ er) {
    __shared__ unsigned short As[64 * LDK];
    __shared__ unsigned short Bs[64 * LDK];
    int p  = blockIdx.z;
    int n0 = blockIdx.x * 64;
    int m0 = blockIdx.y * 64;
    const unsigned short* Bt = fcT + (size_t)p * HD * INF_;
    unsigned short* C = featb + (size_t)p * NN * HD;
    int tid  = threadIdx.x;
    int wv   = tid >> 6, lane = tid & 63;
    int row  = tid >> 2, kc = (tid & 3) * 8;     // staging: 64 rows x 32 k
    int l16  = lane & 15, quad = lane >> 4;
    int mw   = wv * 16;
    f32x4 acc[4] = {{0.f,0.f,0.f,0.f},{0.f,0.f,0.f,0.f},
                    {0.f,0.f,0.f,0.f},{0.f,0.f,0.f,0.f}};
    for (int k0 = 0; k0 < INF_; k0 += 32) {
        *(short8*)&As[row * LDK + kc] =
            *(const short8*)&hb[(size_t)(m0 + row) * INF_ + k0 + kc];
        *(short8*)&Bs[row * LDK + kc] =
            *(const short8*)&Bt[(size_t)(n0 + row) * INF_ + k0 + kc];
        __syncthreads();
        short8 af = *(short8*)&As[(mw + l16) * LDK + quad * 8];
#pragma unroll
        for (int nt = 0; nt < 4; ++nt) {
            short8 bf = *(short8*)&Bs[(nt * 16 + l16) * LDK + quad * 8];
            acc[nt] = __builtin_amdgcn_mfma_f32_16x16x32_bf16(af, bf, acc[nt], 0, 0, 0);
        }
        __syncthreads();
    }
    // D layout: col = nt*16 + l16, row = mw + quad*4 + r
#pragma unroll
    for (int nt = 0; nt < 4; ++nt) {
#pragma unroll
        for (int r = 0; r < 4; ++r) {
            C[(size_t)(m0 + mw + quad * 4 + r) * HD + n0 + nt * 16 + l16] =
                f2bf(acc[nt][r]);
        }
    }
    // fused el/er: head h = n0/64 fully contained in this block's n-tile
    int hidx = n0 >> 6;
    float alv[4], arv[4];
#pragma unroll
    for (int nt = 0; nt < 4; ++nt) {
        alv[nt] = al_all[p * HD + n0 + nt * 16 + l16];
        arv[nt] = ar_all[p * HD + n0 + nt * 16 + l16];
    }
    float* elp = el + (size_t)p * NN * HEADS;
    float* erp = er + (size_t)p * NN * HEADS;
#pragma unroll
    for (int r = 0; r < 4; ++r) {
        float pe = acc[0][r] * alv[0] + acc[1][r] * alv[1] +
                   acc[2][r] * alv[2] + acc[3][r] * alv[3];
        float pr = acc[0][r] * arv[0] + acc[1][r] * arv[1] +
                   acc[2][r] * arv[2] + acc[3][r] * arv[3];
#pragma unroll
        for (int m = 1; m < 16; m <<= 1) {
            pe += __shfl_xor(pe, m);
            pr += __shfl_xor(pr, m);
        }
        if (l16 == 0) {
            int node = m0 + mw + quad * 4 + r;
            elp[node * HEADS + hidx] = pe;
            erp[node * HEADS + hidx] = pr;
        }
    }
}

// ---- K4: FUSED edge softmax + aggregation, ONE WAVE PER (dst,p) ----
// 4 waves/block; lane covers 8 cols (uint4 = 16B bf16) all in head lane>>3.
__global__ __launch_bounds__(256) void fused_attn_rst(
        const int* __restrict__ ssrc_sorted, const int* __restrict__ offsets_all,
        const float* __restrict__ el, const float* __restrict__ er,
        const unsigned short* __restrict__ featb,
        const float* __restrict__ bias_all, const float* __restrict__ v,
        float* __restrict__ alpha_all /* dst-sorted order */,
        unsigned short* __restrict__ zpb,
        float* __restrict__ wsum /* [3][64] bins */) {
    __shared__ float sh_e[4][DEGCAP * 8];
    __shared__ int   sh_src[4][DEGCAP];
    int wv = threadIdx.x >> 6, lane = threadIdx.x & 63;
    int gid = blockIdx.x * 4 + wv;         // over NN*PP
    int n = gid & (NN - 1);
    int p = gid >> 13;                     // NN = 2^13
    const int* srcrow  = ssrc_sorted + (size_t)p * NE;
    const int* offs    = offsets_all + p * (NN + 1);
    const float* elp   = el + (size_t)p * NN * HEADS;
    const float* erp   = er + (size_t)p * NN * HEADS;
    const unsigned short* feat = featb + (size_t)p * NN * HD;
    int start = offs[n];
    int deg = offs[n + 1] - start;
    if (deg > DEGCAP) deg = DEGCAP;        // 16-sigma safe

    // Phase A: one sequential src read per edge; leaky-relu scores into LDS
    for (int t = lane; t < deg; t += 64) {
        int s = srcrow[start + t];
        sh_src[wv][t] = s;
        float4 l0 = *(const float4*)(elp + s * 8);
        float4 l1 = *(const float4*)(elp + s * 8 + 4);
        float4 r0 = *(const float4*)(erp + n * 8);
        float4 r1 = *(const float4*)(erp + n * 8 + 4);
        float sc[8] = {l0.x + r0.x, l0.y + r0.y, l0.z + r0.z, l0.w + r0.w,
                       l1.x + r1.x, l1.y + r1.y, l1.z + r1.z, l1.w + r1.w};
#pragma unroll
        for (int hh = 0; hh < 8; ++hh) {
            float x = sc[hh];
            sh_e[wv][t * 8 + hh] = x > 0.f ? x : 0.2f * x;
        }
    }
    __syncthreads();

    // Phase B: per-head softmax; 8 lanes per head (h = lane>>3, j = lane&7)
    int h = lane >> 3;
    {
        int j = lane & 7;
        float m = -INFINITY;
        for (int t = j; t < deg; t += 8) m = fmaxf(m, sh_e[wv][t * 8 + h]);
#pragma unroll
        for (int off = 4; off; off >>= 1) m = fmaxf(m, __shfl_xor(m, off));
        float ssum = 0.f;
        for (int t = j; t < deg; t += 8) {
            float ee = __expf(sh_e[wv][t * 8 + h] - m);
            sh_e[wv][t * 8 + h] = ee;
            ssum += ee;
        }
#pragma unroll
        for (int off = 4; off; off >>= 1) ssum += __shfl_xor(ssum, off);
        float inv = 1.f / ssum;
        for (int t = j; t < deg; t += 8) sh_e[wv][t * 8 + h] *= inv;
    }
    __syncthreads();

    // Phase C: alpha = mean over heads — fully coalesced write
    for (int t = lane; t < deg; t += 64) {
        float s = 0.f;
#pragma unroll
        for (int hh = 0; hh < 8; ++hh) s += sh_e[wv][t * 8 + hh];
        alpha_all[(size_t)p * NE + start + t] = s * 0.125f;
    }

    // Phase D: lane covers cols c..c+7 (head h); one 16B load per edge row
    int c = lane * 8;
    float acc[8] = {0.f, 0.f, 0.f, 0.f, 0.f, 0.f, 0.f, 0.f};
    for (int k = 0; k < deg; ++k) {
        int s = sh_src[wv][k];
        float a = sh_e[wv][k * 8 + h];
        uint4 f = *(const uint4*)&feat[(size_t)s * HD + c];
        acc[0] += a * bf2f_lo(f.x); acc[1] += a * bf2f_hi(f.x);
        acc[2] += a * bf2f_lo(f.y); acc[3] += a * bf2f_hi(f.y);
        acc[4] += a * bf2f_lo(f.z); acc[5] += a * bf2f_hi(f.z);
        acc[6] += a * bf2f_lo(f.w); acc[7] += a * bf2f_hi(f.w);
    }
    const float* bias = bias_all + p * HD;
    float4 b0 = *(const float4*)(bias + c);
    float4 b1 = *(const float4*)(bias + c + 4);
    float z[8];
    z[0] = acc[0] + b0.x; z[1] = acc[1] + b0.y; z[2] = acc[2] + b0.z; z[3] = acc[3] + b0.w;
    z[4] = acc[4] + b1.x; z[5] = acc[5] + b1.y; z[6] = acc[6] + b1.z; z[7] = acc[7] + b1.w;
#pragma unroll
    for (int i = 0; i < 8; ++i) z[i] = z[i] > 0.f ? z[i] : expm1f(z[i]);
    uint4 zo;
    zo.x = (unsigned)f2bf(z[0]) | ((unsigned)f2bf(z[1]) << 16);
    zo.y = (unsigned)f2bf(z[2]) | ((unsigned)f2bf(z[3]) << 16);
    zo.z = (unsigned)f2bf(z[4]) | ((unsigned)f2bf(z[5]) << 16);
    zo.w = (unsigned)f2bf(z[6]) | ((unsigned)f2bf(z[7]) << 16);
    *(uint4*)&zpb[(size_t)n * (PP * HD) + p * HD + c] = zo;

    // Phase E: semantic-attention partial — wave-reduce dot(z, v)
    float4 v0 = *(const float4*)(v + c);
    float4 v1 = *(const float4*)(v + c + 4);
    float part = z[0] * v0.x + z[1] * v0.y + z[2] * v0.z + z[3] * v0.w +
                 z[4] * v1.x + z[5] * v1.y + z[6] * v1.z + z[7] * v1.w;
#pragma unroll
    for (int off = 32; off > 0; off >>= 1) part += __shfl_down(part, off);
    if (lane == 0) {
        float w = part + v[HD];             // + c0
        w = w > 0.f ? w : 0.01f * w;        // leaky_relu 0.01 BEFORE mean
        atomicAdd(&wsum[p * 64 + (n & 63)], w);
    }
}

// ---- K5: beta (inline) ; z = sum_p beta_p*zp_p ; out = z @ pred_w + pred_b ----
__global__ __launch_bounds__(256) void final_out(
        const unsigned short* __restrict__ zpb, const float* __restrict__ wsum,
        const float* __restrict__ pw, const float* __restrict__ pb,
        float* __restrict__ out) {
    __shared__ float zsh[HD];
    __shared__ float part[256];
    __shared__ float shb[3];
    beta_from_wsum(wsum, shb);
    int n = blockIdx.x, tid = threadIdx.x;
    float b0 = shb[0], b1 = shb[1], b2 = shb[2];
    const unsigned short* zr = zpb + (size_t)n * (PP * HD);
    int c = tid * 2;
    unsigned u0 = *(const unsigned*)(zr + c);
    unsigned u1 = *(const unsigned*)(zr + HD + c);
    unsigned u2 = *(const unsigned*)(zr + 2 * HD + c);
    zsh[c]     = b0 * bf2f_lo(u0) + b1 * bf2f_lo(u1) + b2 * bf2f_lo(u2);
    zsh[c + 1] = b0 * bf2f_hi(u0) + b1 * bf2f_hi(u1) + b2 * bf2f_hi(u2);
    __syncthreads();
    int o = tid & 63, w = tid >> 6;
    float s = 0.f;
    for (int j = w * 128; j < w * 128 + 128; ++j) s += zsh[j] * pw[j * 64 + o];
    part[tid] = s;
    __syncthreads();
    if (tid < 64)
        out[(size_t)n * 64 + o] =
            part[o] + part[64 + o] + part[128 + o] + part[192 + o] + pb[o];
}

// ---- K6: atten row builder — payloads are (alpha-pos, dst): no random edst ----
__global__ __launch_bounds__(256) void atten_rows(
        const int* __restrict__ ssorted, const int* __restrict__ sdst,
        const int* __restrict__ soffs, const float* __restrict__ alpha,
        const float* __restrict__ wsum, float* __restrict__ atten) {
    __shared__ float rowbuf[NN];
    __shared__ float shb[3];
    beta_from_wsum(wsum, shb);
    int srow = blockIdx.x, tid = threadIdx.x;
    f32x4 zero = {0.f, 0.f, 0.f, 0.f};
    for (int j = tid; j < NN / 4; j += 256) ((f32x4*)rowbuf)[j] = zero;
    __syncthreads();
    int s0 = soffs[srow], s1 = soffs[srow + 1];
    for (int k = s0 + tid; k < s1; k += 256) {
        int aidx = ssorted[k];
        int d = sdst[k];
        float val = alpha[aidx] * shb[aidx >> 18];
        atomicAdd(&rowbuf[d], val);
    }
    __syncthreads();
    float* orow = atten + (size_t)srow * NN;
    for (int j = tid * 4; j < NN; j += 1024) {
        f32x4 v = *(f32x4*)(rowbuf + j);
        __builtin_nontemporal_store(v, (f32x4*)(orow + j));
    }
}

extern "C" void kernel_launch(void* const* d_in, const int* in_sizes, int n_in,
                              void* d_out, int out_size, void* d_ws, size_t ws_size,
                              hipStream_t stream) {
    const float* h    = (const float*)d_in[0];
    const int*   esrc = (const int*)d_in[1];
    const int*   edst = (const int*)d_in[2];
    const float* fc   = (const float*)d_in[3];
    const float* al   = (const float*)d_in[4];
    const float* ar   = (const float*)d_in[5];
    const float* bias = (const float*)d_in[6];
    const float* w1   = (const float*)d_in[7];
    const float* b1   = (const float*)d_in[8];
    const float* w2   = (const float*)d_in[9];
    const float* pw   = (const float*)d_in[10];
    const float* pb   = (const float*)d_in[11];
    float* out   = (float*)d_out;
    float* atten = out + (size_t)NN * OUTF;

    char* ws = (char*)d_ws;
    size_t off = 0;
    auto alloc = [&](size_t bytes) {
        void* p = ws + off;
        off = (off + bytes + 255) & ~(size_t)255;
        return p;
    };
    unsigned short* zpb   = (unsigned short*)alloc(sizeof(short) * (size_t)NN * PP * HD);  // 24 MB
    unsigned short* featb = (unsigned short*)alloc(sizeof(short) * (size_t)PP * NN * HD);  // 24 MB
    unsigned short* hb  = (unsigned short*)alloc(sizeof(short) * (size_t)NN * INF_);       // 4 MB
    unsigned short* fcT = (unsigned short*)alloc(sizeof(short) * (size_t)PP * HD * INF_);  // 768 KB
    float*  el      = (float*)alloc(sizeof(float) * PP * NN * HEADS);
    float*  er      = (float*)alloc(sizeof(float) * PP * NN * HEADS);
    float*  alpha   = (float*)alloc(sizeof(float) * (size_t)PP * NE);       // 3 MB (dst-sorted)
    int*    counts  = (int*)alloc(sizeof(int) * 4 * NN);                    // 128 KB
    float*  wsum    = (float*)alloc(sizeof(float) * 3 * 64);                // right after counts
    int*    offsets = (int*)alloc(sizeof(int) * 4 * (NN + 1));
    int*    cursor  = (int*)alloc(sizeof(int) * 4 * NN);
    int*    ssrc_sorted = (int*)alloc(sizeof(int) * (size_t)PP * NE);       // 3 MB (dst CSR: src vals)
    int*    ssorted = (int*)alloc(sizeof(int) * (size_t)PP * NE);           // 3 MB (src CSR: alpha pos)
    int*    sdst    = (int*)alloc(sizeof(int) * (size_t)PP * NE);           // 3 MB (src CSR: dst vals)
    float*  vbuf    = (float*)alloc(sizeof(float) * (HD + 1));

    // zero counts (4 segs) + wsum bins in one memset (contiguous allocs)
    (void)hipMemsetAsync(counts, 0, sizeof(int) * 4 * NN + 1024, stream);

    // casts + LDS-histogram counts in one launch
    cast_count<<<2048 + 1536 + 16, 256, 0, stream>>>(
        h, fc, esrc, edst, hb, fcT, counts);

    // scans (4 segs) + collapsed semantic vector
    scan_vw<<<5, 1024, 0, stream>>>(counts, offsets, cursor, w1, b1, w2, vbuf);

    // CSR scatter: dst CSR (src values) + src CSR (alpha-pos, dst)
    scatter_all<<<PP * NE / 256, 256, 0, stream>>>(
        esrc, edst, cursor, ssrc_sorted, ssorted, sdst);

    // features (bf16 out) + fused attention logits
    gemm_feat_mfma<<<dim3(HD / 64, NN / 64, PP), 256, 0, stream>>>(
        hb, fcT, al, ar, featb, el, er);

    // fused edge-softmax + aggregation + elu + semantic-w partials
    fused_attn_rst<<<NN * PP / 4, 256, 0, stream>>>(
        ssrc_sorted, offsets, el, er, featb, bias, vbuf, alpha, zpb, wsum);

    // outputs (beta computed inline from wsum in both kernels)
    final_out<<<NN, 256, 0, stream>>>(zpb, wsum, pw, pb, out);
    atten_rows<<<NN, 256, 0, stream>>>(
        ssorted, sdst, offsets + 3 * (NN + 1), alpha, wsum, atten);
}

// Round 10
// 752.575 us; speedup vs baseline: 1.3107x; 1.3107x over previous
//
#include <hip/hip_runtime.h>
#include <math.h>

#define NN    8192      // nodes
#define PP    3         // meta-paths
#define INF_  256       // input features
#define HID_  64
#define HEADS 8
#define OUTF  64
#define NE    262144    // edges per path (2^18)
#define HD    512       // HEADS*HID
#define DEGCAP 128      // multinomial(262144,8192): mean 32, max ~70; 128 is 16 sigma

typedef __attribute__((ext_vector_type(8))) short short8;
typedef __attribute__((ext_vector_type(4))) float f32x4;

// round-to-nearest-even fp32 -> bf16
__device__ __forceinline__ unsigned short f2bf(float f) {
    unsigned u = __float_as_uint(f);
    unsigned r = u + 0x7fffu + ((u >> 16) & 1u);
    return (unsigned short)(r >> 16);
}
__device__ __forceinline__ float bf2f_lo(unsigned v) { return __uint_as_float(v << 16); }
__device__ __forceinline__ float bf2f_hi(unsigned v) { return __uint_as_float(v & 0xffff0000u); }

// beta from wsum bins (identical fp32 sequence in every consumer kernel)
__device__ __forceinline__ void beta_from_wsum(
        const float* __restrict__ wsum, float* __restrict__ shb) {
    int tid = threadIdx.x;
    if (tid < 64) {
        float s0 = wsum[tid], s1 = wsum[64 + tid], s2 = wsum[128 + tid];
#pragma unroll
        for (int off = 32; off > 0; off >>= 1) {
            s0 += __shfl_down(s0, off);
            s1 += __shfl_down(s1, off);
            s2 += __shfl_down(s2, off);
        }
        if (tid == 0) {
            float w0 = s0 / (float)NN, w1 = s1 / (float)NN, w2 = s2 / (float)NN;
            float m  = fmaxf(w0, fmaxf(w1, w2));
            float e0 = expf(w0 - m), e1 = expf(w1 - m), e2 = expf(w2 - m);
            float ss = e0 + e1 + e2;
            shb[0] = e0 / ss; shb[1] = e1 / ss; shb[2] = e2 / ss;
        }
    }
    __syncthreads();
}

// ---- K0: cast h->bf16, cast+transpose fc->fcT, dst/src histograms (global) ----
__global__ __launch_bounds__(256) void cast_count(
        const float* __restrict__ h, const float* __restrict__ fc,
        const int* __restrict__ esrc, const int* __restrict__ edst,
        unsigned short* __restrict__ hb, unsigned short* __restrict__ fcT,
        int* __restrict__ counts /* [4][NN] */) {
    int b = blockIdx.x, t = threadIdx.x;
    if (b < 2048) {                               // h: 2M elems, float4
        int i = b * 256 + t;
        float4 v = *(const float4*)(h + (size_t)i * 4);
        ushort4 o = { f2bf(v.x), f2bf(v.y), f2bf(v.z), f2bf(v.w) };
        *(ushort4*)(hb + (size_t)i * 4) = o;
    } else if (b < 2048 + 1536) {                 // fc: 393216 elems, transpose
        int i = (b - 2048) * 256 + t;
        if (i < PP * INF_ * HD) {
            int p = i / (INF_ * HD);
            int rem = i - p * INF_ * HD;
            int k = rem / HD;
            int n = rem - k * HD;
            fcT[(size_t)p * HD * INF_ + (size_t)n * INF_ + k] = f2bf(fc[i]);
        }
    } else {                                      // edges: global-atomic histograms
        int i = (b - 3584) * 256 + t;
        if (i < PP * NE) {
            int p = i >> 18;
            atomicAdd(&counts[p * NN + edst[i]], 1);
            atomicAdd(&counts[3 * NN + esrc[i]], 1);
        }
    }
}

// ---- K1: exclusive scans (blocks 0..3) + collapsed semantic vec (block 4) ----
__global__ __launch_bounds__(1024) void scan_vw(
        const int* __restrict__ counts, int* __restrict__ offsets,
        int* __restrict__ cursor, const float* __restrict__ w1,
        const float* __restrict__ b1, const float* __restrict__ w2,
        float* __restrict__ v /* [513] */) {
    int t = threadIdx.x;
    if (blockIdx.x == 4) {
        if (t < HD) {
            float s = 0.f;
            for (int k = 0; k < 128; ++k) s += w1[t * 128 + k] * w2[k];
            v[t] = s;
        } else if (t == HD) {
            float c = 0.f;
            for (int k = 0; k < 128; ++k) c += b1[k] * w2[k];
            v[HD] = c;
        }
        return;
    }
    __shared__ int sh[1024];
    int seg = blockIdx.x;
    const int* cnt = counts + seg * NN;
    int* offs = offsets + seg * (NN + 1);
    int* cur  = cursor + seg * NN;
    int loc[8];
    int s = 0;
#pragma unroll
    for (int i = 0; i < 8; ++i) { loc[i] = cnt[t * 8 + i]; s += loc[i]; }
    sh[t] = s;
    __syncthreads();
    for (int off = 1; off < 1024; off <<= 1) {
        int vv = (t >= off) ? sh[t - off] : 0;
        __syncthreads();
        sh[t] += vv;
        __syncthreads();
    }
    int run = sh[t] - s;
#pragma unroll
    for (int i = 0; i < 8; ++i) {
        offs[t * 8 + i] = run;
        cur[t * 8 + i]  = run;
        run += loc[i];
    }
    if (t == 1023) offs[NN] = run;
}

// ---- K2: scatter — dst-CSR stores SRC VALUES; src-CSR stores (alpha-pos, dst) ----
__global__ __launch_bounds__(256) void scatter_all(
        const int* __restrict__ esrc, const int* __restrict__ edst,
        int* __restrict__ cursor, int* __restrict__ ssrc_sorted,
        int* __restrict__ ssorted, int* __restrict__ sdst) {
    int i = blockIdx.x * blockDim.x + threadIdx.x;
    if (i >= PP * NE) return;
    int p = i >> 18;
    int s = esrc[i], d = edst[i];
    int pos = atomicAdd(&cursor[p * NN + d], 1);
    ssrc_sorted[(size_t)p * NE + pos] = s;     // src value directly
    int pos2 = atomicAdd(&cursor[3 * NN + s], 1);
    ssorted[pos2] = p * NE + pos;              // alpha position (dst-sorted)
    sdst[pos2]    = d;
}

// ---- K3: feat[p] = h @ fc_p  via bf16 MFMA; bf16 feat out + fused el/er ----
#define LDK 56   // padded LDS row stride (bf16): 112B rows, 16B-aligned
__global__ __launch_bounds__(256) void gemm_feat_mfma(
        const unsigned short* __restrict__ hb,   // [NN, INF_] bf16
        const unsigned short* __restrict__ fcT,  // [PP, HD, INF_] bf16
        const float* __restrict__ al_all,        // [PP, HD]
        const float* __restrict__ ar_all,        // [PP, HD]
        unsigned short* __restrict__ featb,      // [PP, NN, HD] bf16
        float* __restrict__ el,                  // [PP, NN, HEADS]
        float* __restrict__ er) {
    __shared__ unsigned short As[64 * LDK];
    __shared__ unsigned short Bs[64 * LDK];
    int p  = blockIdx.z;
    int n0 = blockIdx.x * 64;
    int m0 = blockIdx.y * 64;
    const unsigned short* Bt = fcT + (size_t)p * HD * INF_;
    unsigned short* C = featb + (size_t)p * NN * HD;
    int tid  = threadIdx.x;
    int wv   = tid >> 6, lane = tid & 63;
    int row  = tid >> 2, kc = (tid & 3) * 8;     // staging: 64 rows x 32 k
    int l16  = lane & 15, quad = lane >> 4;
    int mw   = wv * 16;
    f32x4 acc[4] = {{0.f,0.f,0.f,0.f},{0.f,0.f,0.f,0.f},
                    {0.f,0.f,0.f,0.f},{0.f,0.f,0.f,0.f}};
    for (int k0 = 0; k0 < INF_; k0 += 32) {
        *(short8*)&As[row * LDK + kc] =
            *(const short8*)&hb[(size_t)(m0 + row) * INF_ + k0 + kc];
        *(short8*)&Bs[row * LDK + kc] =
            *(const short8*)&Bt[(size_t)(n0 + row) * INF_ + k0 + kc];
        __syncthreads();
        short8 af = *(short8*)&As[(mw + l16) * LDK + quad * 8];
#pragma unroll
        for (int nt = 0; nt < 4; ++nt) {
            short8 bf = *(short8*)&Bs[(nt * 16 + l16) * LDK + quad * 8];
            acc[nt] = __builtin_amdgcn_mfma_f32_16x16x32_bf16(af, bf, acc[nt], 0, 0, 0);
        }
        __syncthreads();
    }
    // D layout: col = nt*16 + l16, row = mw + quad*4 + r
#pragma unroll
    for (int nt = 0; nt < 4; ++nt) {
#pragma unroll
        for (int r = 0; r < 4; ++r) {
            C[(size_t)(m0 + mw + quad * 4 + r) * HD + n0 + nt * 16 + l16] =
                f2bf(acc[nt][r]);
        }
    }
    // fused el/er: head h = n0/64 fully contained in this block's n-tile
    int hidx = n0 >> 6;
    float alv[4], arv[4];
#pragma unroll
    for (int nt = 0; nt < 4; ++nt) {
        alv[nt] = al_all[p * HD + n0 + nt * 16 + l16];
        arv[nt] = ar_all[p * HD + n0 + nt * 16 + l16];
    }
    float* elp = el + (size_t)p * NN * HEADS;
    float* erp = er + (size_t)p * NN * HEADS;
#pragma unroll
    for (int r = 0; r < 4; ++r) {
        float pe = acc[0][r] * alv[0] + acc[1][r] * alv[1] +
                   acc[2][r] * alv[2] + acc[3][r] * alv[3];
        float pr = acc[0][r] * arv[0] + acc[1][r] * arv[1] +
                   acc[2][r] * arv[2] + acc[3][r] * arv[3];
#pragma unroll
        for (int m = 1; m < 16; m <<= 1) {
            pe += __shfl_xor(pe, m);
            pr += __shfl_xor(pr, m);
        }
        if (l16 == 0) {
            int node = m0 + mw + quad * 4 + r;
            elp[node * HEADS + hidx] = pe;
            erp[node * HEADS + hidx] = pr;
        }
    }
}

// ---- K4: FUSED edge softmax + aggregation, ONE WAVE PER (dst,p) ----
// 4 waves/block; lane covers 8 cols (uint4 = 16B bf16) all in head lane>>3.
__global__ __launch_bounds__(256) void fused_attn_rst(
        const int* __restrict__ ssrc_sorted, const int* __restrict__ offsets_all,
        const float* __restrict__ el, const float* __restrict__ er,
        const unsigned short* __restrict__ featb,
        const float* __restrict__ bias_all, const float* __restrict__ v,
        float* __restrict__ alpha_all /* dst-sorted order */,
        unsigned short* __restrict__ zpb,
        float* __restrict__ wsum /* [3][64] bins */) {
    __shared__ float sh_e[4][DEGCAP * 8];
    __shared__ int   sh_src[4][DEGCAP];
    int wv = threadIdx.x >> 6, lane = threadIdx.x & 63;
    int gid = blockIdx.x * 4 + wv;         // over NN*PP
    int n = gid & (NN - 1);
    int p = gid >> 13;                     // NN = 2^13
    const int* srcrow  = ssrc_sorted + (size_t)p * NE;
    const int* offs    = offsets_all + p * (NN + 1);
    const float* elp   = el + (size_t)p * NN * HEADS;
    const float* erp   = er + (size_t)p * NN * HEADS;
    const unsigned short* feat = featb + (size_t)p * NN * HD;
    int start = offs[n];
    int deg = offs[n + 1] - start;
    if (deg > DEGCAP) deg = DEGCAP;        // 16-sigma safe

    // Phase A: one sequential src read per edge; leaky-relu scores into LDS
    for (int t = lane; t < deg; t += 64) {
        int s = srcrow[start + t];
        sh_src[wv][t] = s;
        float4 l0 = *(const float4*)(elp + s * 8);
        float4 l1 = *(const float4*)(elp + s * 8 + 4);
        float4 r0 = *(const float4*)(erp + n * 8);
        float4 r1 = *(const float4*)(erp + n * 8 + 4);
        float sc[8] = {l0.x + r0.x, l0.y + r0.y, l0.z + r0.z, l0.w + r0.w,
                       l1.x + r1.x, l1.y + r1.y, l1.z + r1.z, l1.w + r1.w};
#pragma unroll
        for (int hh = 0; hh < 8; ++hh) {
            float x = sc[hh];
            sh_e[wv][t * 8 + hh] = x > 0.f ? x : 0.2f * x;
        }
    }
    __syncthreads();

    // Phase B: per-head softmax; 8 lanes per head (h = lane>>3, j = lane&7)
    int h = lane >> 3;
    {
        int j = lane & 7;
        float m = -INFINITY;
        for (int t = j; t < deg; t += 8) m = fmaxf(m, sh_e[wv][t * 8 + h]);
#pragma unroll
        for (int off = 4; off; off >>= 1) m = fmaxf(m, __shfl_xor(m, off));
        float ssum = 0.f;
        for (int t = j; t < deg; t += 8) {
            float ee = __expf(sh_e[wv][t * 8 + h] - m);
            sh_e[wv][t * 8 + h] = ee;
            ssum += ee;
        }
#pragma unroll
        for (int off = 4; off; off >>= 1) ssum += __shfl_xor(ssum, off);
        float inv = 1.f / ssum;
        for (int t = j; t < deg; t += 8) sh_e[wv][t * 8 + h] *= inv;
    }
    __syncthreads();

    // Phase C: alpha = mean over heads — fully coalesced write
    for (int t = lane; t < deg; t += 64) {
        float s = 0.f;
#pragma unroll
        for (int hh = 0; hh < 8; ++hh) s += sh_e[wv][t * 8 + hh];
        alpha_all[(size_t)p * NE + start + t] = s * 0.125f;
    }

    // Phase D: lane covers cols c..c+7 (head h); one 16B load per edge row
    int c = lane * 8;
    float acc[8] = {0.f, 0.f, 0.f, 0.f, 0.f, 0.f, 0.f, 0.f};
    for (int k = 0; k < deg; ++k) {
        int s = sh_src[wv][k];
        float a = sh_e[wv][k * 8 + h];
        uint4 f = *(const uint4*)&feat[(size_t)s * HD + c];
        acc[0] += a * bf2f_lo(f.x); acc[1] += a * bf2f_hi(f.x);
        acc[2] += a * bf2f_lo(f.y); acc[3] += a * bf2f_hi(f.y);
        acc[4] += a * bf2f_lo(f.z); acc[5] += a * bf2f_hi(f.z);
        acc[6] += a * bf2f_lo(f.w); acc[7] += a * bf2f_hi(f.w);
    }
    const float* bias = bias_all + p * HD;
    float4 b0 = *(const float4*)(bias + c);
    float4 b1 = *(const float4*)(bias + c + 4);
    float z[8];
    z[0] = acc[0] + b0.x; z[1] = acc[1] + b0.y; z[2] = acc[2] + b0.z; z[3] = acc[3] + b0.w;
    z[4] = acc[4] + b1.x; z[5] = acc[5] + b1.y; z[6] = acc[6] + b1.z; z[7] = acc[7] + b1.w;
#pragma unroll
    for (int i = 0; i < 8; ++i) z[i] = z[i] > 0.f ? z[i] : expm1f(z[i]);
    uint4 zo;
    zo.x = (unsigned)f2bf(z[0]) | ((unsigned)f2bf(z[1]) << 16);
    zo.y = (unsigned)f2bf(z[2]) | ((unsigned)f2bf(z[3]) << 16);
    zo.z = (unsigned)f2bf(z[4]) | ((unsigned)f2bf(z[5]) << 16);
    zo.w = (unsigned)f2bf(z[6]) | ((unsigned)f2bf(z[7]) << 16);
    *(uint4*)&zpb[(size_t)n * (PP * HD) + p * HD + c] = zo;

    // Phase E: semantic-attention partial — wave-reduce dot(z, v)
    float4 v0 = *(const float4*)(v + c);
    float4 v1 = *(const float4*)(v + c + 4);
    float part = z[0] * v0.x + z[1] * v0.y + z[2] * v0.z + z[3] * v0.w +
                 z[4] * v1.x + z[5] * v1.y + z[6] * v1.z + z[7] * v1.w;
#pragma unroll
    for (int off = 32; off > 0; off >>= 1) part += __shfl_down(part, off);
    if (lane == 0) {
        float w = part + v[HD];             // + c0
        w = w > 0.f ? w : 0.01f * w;        // leaky_relu 0.01 BEFORE mean
        atomicAdd(&wsum[p * 64 + (n & 63)], w);
    }
}

// ---- K5: beta (inline) ; z = sum_p beta_p*zp_p ; out = z @ pred_w + pred_b ----
__global__ __launch_bounds__(256) void final_out(
        const unsigned short* __restrict__ zpb, const float* __restrict__ wsum,
        const float* __restrict__ pw, const float* __restrict__ pb,
        float* __restrict__ out) {
    __shared__ float zsh[HD];
    __shared__ float part[256];
    __shared__ float shb[3];
    beta_from_wsum(wsum, shb);
    int n = blockIdx.x, tid = threadIdx.x;
    float b0 = shb[0], b1 = shb[1], b2 = shb[2];
    const unsigned short* zr = zpb + (size_t)n * (PP * HD);
    int c = tid * 2;
    unsigned u0 = *(const unsigned*)(zr + c);
    unsigned u1 = *(const unsigned*)(zr + HD + c);
    unsigned u2 = *(const unsigned*)(zr + 2 * HD + c);
    zsh[c]     = b0 * bf2f_lo(u0) + b1 * bf2f_lo(u1) + b2 * bf2f_lo(u2);
    zsh[c + 1] = b0 * bf2f_hi(u0) + b1 * bf2f_hi(u1) + b2 * bf2f_hi(u2);
    __syncthreads();
    int o = tid & 63, w = tid >> 6;
    float s = 0.f;
    for (int j = w * 128; j < w * 128 + 128; ++j) s += zsh[j] * pw[j * 64 + o];
    part[tid] = s;
    __syncthreads();
    if (tid < 64)
        out[(size_t)n * 64 + o] =
            part[o] + part[64 + o] + part[128 + o] + part[192 + o] + pb[o];
}

// ---- K6: atten row builder — payloads are (alpha-pos, dst): no random edst ----
__global__ __launch_bounds__(256) void atten_rows(
        const int* __restrict__ ssorted, const int* __restrict__ sdst,
        const int* __restrict__ soffs, const float* __restrict__ alpha,
        const float* __restrict__ wsum, float* __restrict__ atten) {
    __shared__ float rowbuf[NN];
    __shared__ float shb[3];
    beta_from_wsum(wsum, shb);
    int srow = blockIdx.x, tid = threadIdx.x;
    f32x4 zero = {0.f, 0.f, 0.f, 0.f};
    for (int j = tid; j < NN / 4; j += 256) ((f32x4*)rowbuf)[j] = zero;
    __syncthreads();
    int s0 = soffs[srow], s1 = soffs[srow + 1];
    for (int k = s0 + tid; k < s1; k += 256) {
        int aidx = ssorted[k];
        int d = sdst[k];
        float val = alpha[aidx] * shb[aidx >> 18];
        atomicAdd(&rowbuf[d], val);
    }
    __syncthreads();
    float* orow = atten + (size_t)srow * NN;
    for (int j = tid * 4; j < NN; j += 1024) {
        f32x4 v = *(f32x4*)(rowbuf + j);
        __builtin_nontemporal_store(v, (f32x4*)(orow + j));
    }
}

extern "C" void kernel_launch(void* const* d_in, const int* in_sizes, int n_in,
                              void* d_out, int out_size, void* d_ws, size_t ws_size,
                              hipStream_t stream) {
    const float* h    = (const float*)d_in[0];
    const int*   esrc = (const int*)d_in[1];
    const int*   edst = (const int*)d_in[2];
    const float* fc   = (const float*)d_in[3];
    const float* al   = (const float*)d_in[4];
    const float* ar   = (const float*)d_in[5];
    const float* bias = (const float*)d_in[6];
    const float* w1   = (const float*)d_in[7];
    const float* b1   = (const float*)d_in[8];
    const float* w2   = (const float*)d_in[9];
    const float* pw   = (const float*)d_in[10];
    const float* pb   = (const float*)d_in[11];
    float* out   = (float*)d_out;
    float* atten = out + (size_t)NN * OUTF;

    char* ws = (char*)d_ws;
    size_t off = 0;
    auto alloc = [&](size_t bytes) {
        void* p = ws + off;
        off = (off + bytes + 255) & ~(size_t)255;
        return p;
    };
    unsigned short* zpb   = (unsigned short*)alloc(sizeof(short) * (size_t)NN * PP * HD);  // 24 MB
    unsigned short* featb = (unsigned short*)alloc(sizeof(short) * (size_t)PP * NN * HD);  // 24 MB
    unsigned short* hb  = (unsigned short*)alloc(sizeof(short) * (size_t)NN * INF_);       // 4 MB
    unsigned short* fcT = (unsigned short*)alloc(sizeof(short) * (size_t)PP * HD * INF_);  // 768 KB
    float*  el      = (float*)alloc(sizeof(float) * PP * NN * HEADS);
    float*  er      = (float*)alloc(sizeof(float) * PP * NN * HEADS);
    float*  alpha   = (float*)alloc(sizeof(float) * (size_t)PP * NE);       // 3 MB (dst-sorted)
    int*    counts  = (int*)alloc(sizeof(int) * 4 * NN);                    // 128 KB
    float*  wsum    = (float*)alloc(sizeof(float) * 3 * 64);                // right after counts
    int*    offsets = (int*)alloc(sizeof(int) * 4 * (NN + 1));
    int*    cursor  = (int*)alloc(sizeof(int) * 4 * NN);
    int*    ssrc_sorted = (int*)alloc(sizeof(int) * (size_t)PP * NE);       // 3 MB (dst CSR: src vals)
    int*    ssorted = (int*)alloc(sizeof(int) * (size_t)PP * NE);           // 3 MB (src CSR: alpha pos)
    int*    sdst    = (int*)alloc(sizeof(int) * (size_t)PP * NE);           // 3 MB (src CSR: dst vals)
    float*  vbuf    = (float*)alloc(sizeof(float) * (HD + 1));

    // zero counts (4 segs) + wsum bins in one memset (contiguous allocs)
    (void)hipMemsetAsync(counts, 0, sizeof(int) * 4 * NN + 1024, stream);

    // casts + global-atomic histograms in one launch
    cast_count<<<2048 + 1536 + 3072, 256, 0, stream>>>(
        h, fc, esrc, edst, hb, fcT, counts);

    // scans (4 segs) + collapsed semantic vector
    scan_vw<<<5, 1024, 0, stream>>>(counts, offsets, cursor, w1, b1, w2, vbuf);

    // CSR scatter: dst CSR (src values) + src CSR (alpha-pos, dst)
    scatter_all<<<PP * NE / 256, 256, 0, stream>>>(
        esrc, edst, cursor, ssrc_sorted, ssorted, sdst);

    // features (bf16 out) + fused attention logits
    gemm_feat_mfma<<<dim3(HD / 64, NN / 64, PP), 256, 0, stream>>>(
        hb, fcT, al, ar, featb, el, er);

    // fused edge-softmax + aggregation + elu + semantic-w partials
    fused_attn_rst<<<NN * PP / 4, 256, 0, stream>>>(
        ssrc_sorted, offsets, el, er, featb, bias, vbuf, alpha, zpb, wsum);

    // outputs (beta computed inline from wsum in both kernels)
    final_out<<<NN, 256, 0, stream>>>(zpb, wsum, pw, pb, out);
    atten_rows<<<NN, 256, 0, stream>>>(
        ssorted, sdst, offsets + 3 * (NN + 1), alpha, wsum, atten);
}

// Round 11
// 701.280 us; speedup vs baseline: 1.4066x; 1.0731x over previous
//
#include <hip/hip_runtime.h>
#include <math.h>

#define NN    8192      // nodes
#define PP    3         // meta-paths
#define INF_  256       // input features
#define HID_  64
#define HEADS 8
#define OUTF  64
#define NE    262144    // edges per path (2^18)
#define HD    512       // HEADS*HID
#define DEGCAP 128      // multinomial(262144,8192): mean 32, max ~70; 128 is 16 sigma

typedef __attribute__((ext_vector_type(8))) short short8;
typedef __attribute__((ext_vector_type(4))) float f32x4;

// round-to-nearest-even fp32 -> bf16
__device__ __forceinline__ unsigned short f2bf(float f) {
    unsigned u = __float_as_uint(f);
    unsigned r = u + 0x7fffu + ((u >> 16) & 1u);
    return (unsigned short)(r >> 16);
}
__device__ __forceinline__ float bf2f_lo(unsigned v) { return __uint_as_float(v << 16); }
__device__ __forceinline__ float bf2f_hi(unsigned v) { return __uint_as_float(v & 0xffff0000u); }

// beta from wsum bins (identical fp32 sequence in every consumer kernel)
__device__ __forceinline__ void beta_from_wsum(
        const float* __restrict__ wsum, float* __restrict__ shb) {
    int tid = threadIdx.x;
    if (tid < 64) {
        float s0 = wsum[tid], s1 = wsum[64 + tid], s2 = wsum[128 + tid];
#pragma unroll
        for (int off = 32; off > 0; off >>= 1) {
            s0 += __shfl_down(s0, off);
            s1 += __shfl_down(s1, off);
            s2 += __shfl_down(s2, off);
        }
        if (tid == 0) {
            float w0 = s0 / (float)NN, w1 = s1 / (float)NN, w2 = s2 / (float)NN;
            float m  = fmaxf(w0, fmaxf(w1, w2));
            float e0 = expf(w0 - m), e1 = expf(w1 - m), e2 = expf(w2 - m);
            float ss = e0 + e1 + e2;
            shb[0] = e0 / ss; shb[1] = e1 / ss; shb[2] = e2 / ss;
        }
    }
    __syncthreads();
}

// ---- K0: cast h->bf16, cast+transpose fc->fcT, dst/src histograms (global) ----
__global__ __launch_bounds__(256) void cast_count(
        const float* __restrict__ h, const float* __restrict__ fc,
        const int* __restrict__ esrc, const int* __restrict__ edst,
        unsigned short* __restrict__ hb, unsigned short* __restrict__ fcT,
        int* __restrict__ counts /* [4][NN] */) {
    int b = blockIdx.x, t = threadIdx.x;
    if (b < 2048) {                               // h: 2M elems, float4
        int i = b * 256 + t;
        float4 v = *(const float4*)(h + (size_t)i * 4);
        ushort4 o = { f2bf(v.x), f2bf(v.y), f2bf(v.z), f2bf(v.w) };
        *(ushort4*)(hb + (size_t)i * 4) = o;
    } else if (b < 2048 + 1536) {                 // fc: 393216 elems, transpose
        int i = (b - 2048) * 256 + t;
        if (i < PP * INF_ * HD) {
            int p = i / (INF_ * HD);
            int rem = i - p * INF_ * HD;
            int k = rem / HD;
            int n = rem - k * HD;
            fcT[(size_t)p * HD * INF_ + (size_t)n * INF_ + k] = f2bf(fc[i]);
        }
    } else {                                      // edges: global-atomic histograms
        int i = (b - 3584) * 256 + t;
        if (i < PP * NE) {
            int p = i >> 18;
            atomicAdd(&counts[p * NN + edst[i]], 1);
            atomicAdd(&counts[3 * NN + esrc[i]], 1);
        }
    }
}

// ---- K1: exclusive scans (blocks 0..3) + collapsed semantic vec (block 4) ----
__global__ __launch_bounds__(1024) void scan_vw(
        const int* __restrict__ counts, int* __restrict__ offsets,
        int* __restrict__ cursor, const float* __restrict__ w1,
        const float* __restrict__ b1, const float* __restrict__ w2,
        float* __restrict__ v /* [513] */) {
    int t = threadIdx.x;
    if (blockIdx.x == 4) {
        if (t < HD) {
            float s = 0.f;
            for (int k = 0; k < 128; ++k) s += w1[t * 128 + k] * w2[k];
            v[t] = s;
        } else if (t == HD) {
            float c = 0.f;
            for (int k = 0; k < 128; ++k) c += b1[k] * w2[k];
            v[HD] = c;
        }
        return;
    }
    __shared__ int sh[1024];
    int seg = blockIdx.x;
    const int* cnt = counts + seg * NN;
    int* offs = offsets + seg * (NN + 1);
    int* cur  = cursor + seg * NN;
    int loc[8];
    int s = 0;
#pragma unroll
    for (int i = 0; i < 8; ++i) { loc[i] = cnt[t * 8 + i]; s += loc[i]; }
    sh[t] = s;
    __syncthreads();
    for (int off = 1; off < 1024; off <<= 1) {
        int vv = (t >= off) ? sh[t - off] : 0;
        __syncthreads();
        sh[t] += vv;
        __syncthreads();
    }
    int run = sh[t] - s;
#pragma unroll
    for (int i = 0; i < 8; ++i) {
        offs[t * 8 + i] = run;
        cur[t * 8 + i]  = run;
        run += loc[i];
    }
    if (t == 1023) offs[NN] = run;
}

// ---- K2: scatter — dst-CSR stores SRC VALUES; src-CSR stores packed (alpha-pos, dst) ----
__global__ __launch_bounds__(256) void scatter_all(
        const int* __restrict__ esrc, const int* __restrict__ edst,
        int* __restrict__ cursor, int* __restrict__ ssrc_sorted,
        int2* __restrict__ spair) {
    int i = blockIdx.x * blockDim.x + threadIdx.x;
    if (i >= PP * NE) return;
    int p = i >> 18;
    int s = esrc[i], d = edst[i];
    int pos = atomicAdd(&cursor[p * NN + d], 1);
    ssrc_sorted[(size_t)p * NE + pos] = s;     // src value directly
    int pos2 = atomicAdd(&cursor[3 * NN + s], 1);
    int2 pr; pr.x = p * NE + pos; pr.y = d;    // alpha pos (dst-sorted) + dst
    spair[pos2] = pr;                          // single 8B scattered store
}

// ---- K3: feat[p] = h @ fc_p  via bf16 MFMA; bf16 feat out + fused el/er ----
#define LDK 56   // padded LDS row stride (bf16): 112B rows, 16B-aligned
__global__ __launch_bounds__(256) void gemm_feat_mfma(
        const unsigned short* __restrict__ hb,   // [NN, INF_] bf16
        const unsigned short* __restrict__ fcT,  // [PP, HD, INF_] bf16
        const float* __restrict__ al_all,        // [PP, HD]
        const float* __restrict__ ar_all,        // [PP, HD]
        unsigned short* __restrict__ featb,      // [PP, NN, HD] bf16
        float* __restrict__ el,                  // [PP, NN, HEADS]
        float* __restrict__ er) {
    __shared__ unsigned short As[64 * LDK];
    __shared__ unsigned short Bs[64 * LDK];
    int p  = blockIdx.z;
    int n0 = blockIdx.x * 64;
    int m0 = blockIdx.y * 64;
    const unsigned short* Bt = fcT + (size_t)p * HD * INF_;
    unsigned short* C = featb + (size_t)p * NN * HD;
    int tid  = threadIdx.x;
    int wv   = tid >> 6, lane = tid & 63;
    int row  = tid >> 2, kc = (tid & 3) * 8;     // staging: 64 rows x 32 k
    int l16  = lane & 15, quad = lane >> 4;
    int mw   = wv * 16;
    f32x4 acc[4] = {{0.f,0.f,0.f,0.f},{0.f,0.f,0.f,0.f},
                    {0.f,0.f,0.f,0.f},{0.f,0.f,0.f,0.f}};
    for (int k0 = 0; k0 < INF_; k0 += 32) {
        *(short8*)&As[row * LDK + kc] =
            *(const short8*)&hb[(size_t)(m0 + row) * INF_ + k0 + kc];
        *(short8*)&Bs[row * LDK + kc] =
            *(const short8*)&Bt[(size_t)(n0 + row) * INF_ + k0 + kc];
        __syncthreads();
        short8 af = *(short8*)&As[(mw + l16) * LDK + quad * 8];
#pragma unroll
        for (int nt = 0; nt < 4; ++nt) {
            short8 bf = *(short8*)&Bs[(nt * 16 + l16) * LDK + quad * 8];
            acc[nt] = __builtin_amdgcn_mfma_f32_16x16x32_bf16(af, bf, acc[nt], 0, 0, 0);
        }
        __syncthreads();
    }
    // D layout: col = nt*16 + l16, row = mw + quad*4 + r
#pragma unroll
    for (int nt = 0; nt < 4; ++nt) {
#pragma unroll
        for (int r = 0; r < 4; ++r) {
            C[(size_t)(m0 + mw + quad * 4 + r) * HD + n0 + nt * 16 + l16] =
                f2bf(acc[nt][r]);
        }
    }
    // fused el/er: head h = n0/64 fully contained in this block's n-tile
    int hidx = n0 >> 6;
    float alv[4], arv[4];
#pragma unroll
    for (int nt = 0; nt < 4; ++nt) {
        alv[nt] = al_all[p * HD + n0 + nt * 16 + l16];
        arv[nt] = ar_all[p * HD + n0 + nt * 16 + l16];
    }
    float* elp = el + (size_t)p * NN * HEADS;
    float* erp = er + (size_t)p * NN * HEADS;
#pragma unroll
    for (int r = 0; r < 4; ++r) {
        float pe = acc[0][r] * alv[0] + acc[1][r] * alv[1] +
                   acc[2][r] * alv[2] + acc[3][r] * alv[3];
        float pr = acc[0][r] * arv[0] + acc[1][r] * arv[1] +
                   acc[2][r] * arv[2] + acc[3][r] * arv[3];
#pragma unroll
        for (int m = 1; m < 16; m <<= 1) {
            pe += __shfl_xor(pe, m);
            pr += __shfl_xor(pr, m);
        }
        if (l16 == 0) {
            int node = m0 + mw + quad * 4 + r;
            elp[node * HEADS + hidx] = pe;
            erp[node * HEADS + hidx] = pr;
        }
    }
}

// ---- K4: FUSED edge softmax + aggregation, ONE WAVE PER (dst,p) ----
// 4 waves/block; lane covers 8 cols (uint4 = 16B bf16) all in head lane>>3.
__global__ __launch_bounds__(256) void fused_attn_rst(
        const int* __restrict__ ssrc_sorted, const int* __restrict__ offsets_all,
        const float* __restrict__ el, const float* __restrict__ er,
        const unsigned short* __restrict__ featb,
        const float* __restrict__ bias_all, const float* __restrict__ v,
        float* __restrict__ alpha_all /* dst-sorted order */,
        unsigned short* __restrict__ zpb,
        float* __restrict__ wsum /* [3][64] bins */) {
    __shared__ float sh_e[4][DEGCAP * 8];
    __shared__ int   sh_src[4][DEGCAP];
    int wv = threadIdx.x >> 6, lane = threadIdx.x & 63;
    int gid = blockIdx.x * 4 + wv;         // over NN*PP
    int n = gid & (NN - 1);
    int p = gid >> 13;                     // NN = 2^13
    const int* srcrow  = ssrc_sorted + (size_t)p * NE;
    const int* offs    = offsets_all + p * (NN + 1);
    const float* elp   = el + (size_t)p * NN * HEADS;
    const float* erp   = er + (size_t)p * NN * HEADS;
    const unsigned short* feat = featb + (size_t)p * NN * HD;
    int start = offs[n];
    int deg = offs[n + 1] - start;
    if (deg > DEGCAP) deg = DEGCAP;        // 16-sigma safe

    // Phase A: one sequential src read per edge; leaky-relu scores into LDS
    for (int t = lane; t < deg; t += 64) {
        int s = srcrow[start + t];
        sh_src[wv][t] = s;
        float4 l0 = *(const float4*)(elp + s * 8);
        float4 l1 = *(const float4*)(elp + s * 8 + 4);
        float4 r0 = *(const float4*)(erp + n * 8);
        float4 r1 = *(const float4*)(erp + n * 8 + 4);
        float sc[8] = {l0.x + r0.x, l0.y + r0.y, l0.z + r0.z, l0.w + r0.w,
                       l1.x + r1.x, l1.y + r1.y, l1.z + r1.z, l1.w + r1.w};
#pragma unroll
        for (int hh = 0; hh < 8; ++hh) {
            float x = sc[hh];
            sh_e[wv][t * 8 + hh] = x > 0.f ? x : 0.2f * x;
        }
    }
    __syncthreads();

    // Phase B: per-head softmax; 8 lanes per head (h = lane>>3, j = lane&7)
    int h = lane >> 3;
    {
        int j = lane & 7;
        float m = -INFINITY;
        for (int t = j; t < deg; t += 8) m = fmaxf(m, sh_e[wv][t * 8 + h]);
#pragma unroll
        for (int off = 4; off; off >>= 1) m = fmaxf(m, __shfl_xor(m, off));
        float ssum = 0.f;
        for (int t = j; t < deg; t += 8) {
            float ee = __expf(sh_e[wv][t * 8 + h] - m);
            sh_e[wv][t * 8 + h] = ee;
            ssum += ee;
        }
#pragma unroll
        for (int off = 4; off; off >>= 1) ssum += __shfl_xor(ssum, off);
        float inv = 1.f / ssum;
        for (int t = j; t < deg; t += 8) sh_e[wv][t * 8 + h] *= inv;
    }
    __syncthreads();

    // Phase C: alpha = mean over heads — fully coalesced write
    for (int t = lane; t < deg; t += 64) {
        float s = 0.f;
#pragma unroll
        for (int hh = 0; hh < 8; ++hh) s += sh_e[wv][t * 8 + hh];
        alpha_all[(size_t)p * NE + start + t] = s * 0.125f;
    }

    // Phase D: lane covers cols c..c+7 (head h); one 16B load per edge row
    int c = lane * 8;
    float acc[8] = {0.f, 0.f, 0.f, 0.f, 0.f, 0.f, 0.f, 0.f};
    for (int k = 0; k < deg; ++k) {
        int s = sh_src[wv][k];
        float a = sh_e[wv][k * 8 + h];
        uint4 f = *(const uint4*)&feat[(size_t)s * HD + c];
        acc[0] += a * bf2f_lo(f.x); acc[1] += a * bf2f_hi(f.x);
        acc[2] += a * bf2f_lo(f.y); acc[3] += a * bf2f_hi(f.y);
        acc[4] += a * bf2f_lo(f.z); acc[5] += a * bf2f_hi(f.z);
        acc[6] += a * bf2f_lo(f.w); acc[7] += a * bf2f_hi(f.w);
    }
    const float* bias = bias_all + p * HD;
    float4 b0 = *(const float4*)(bias + c);
    float4 b1 = *(const float4*)(bias + c + 4);
    float z[8];
    z[0] = acc[0] + b0.x; z[1] = acc[1] + b0.y; z[2] = acc[2] + b0.z; z[3] = acc[3] + b0.w;
    z[4] = acc[4] + b1.x; z[5] = acc[5] + b1.y; z[6] = acc[6] + b1.z; z[7] = acc[7] + b1.w;
#pragma unroll
    for (int i = 0; i < 8; ++i) z[i] = z[i] > 0.f ? z[i] : expm1f(z[i]);
    uint4 zo;
    zo.x = (unsigned)f2bf(z[0]) | ((unsigned)f2bf(z[1]) << 16);
    zo.y = (unsigned)f2bf(z[2]) | ((unsigned)f2bf(z[3]) << 16);
    zo.z = (unsigned)f2bf(z[4]) | ((unsigned)f2bf(z[5]) << 16);
    zo.w = (unsigned)f2bf(z[6]) | ((unsigned)f2bf(z[7]) << 16);
    *(uint4*)&zpb[(size_t)n * (PP * HD) + p * HD + c] = zo;

    // Phase E: semantic-attention partial — wave-reduce dot(z, v)
    float4 v0 = *(const float4*)(v + c);
    float4 v1 = *(const float4*)(v + c + 4);
    float part = z[0] * v0.x + z[1] * v0.y + z[2] * v0.z + z[3] * v0.w +
                 z[4] * v1.x + z[5] * v1.y + z[6] * v1.z + z[7] * v1.w;
#pragma unroll
    for (int off = 32; off > 0; off >>= 1) part += __shfl_down(part, off);
    if (lane == 0) {
        float w = part + v[HD];             // + c0
        w = w > 0.f ? w : 0.01f * w;        // leaky_relu 0.01 BEFORE mean
        atomicAdd(&wsum[p * 64 + (n & 63)], w);
    }
}

// ---- K5: beta (inline) ; z = sum_p beta_p*zp_p ; out = z @ pred_w + pred_b ----
__global__ __launch_bounds__(256) void final_out(
        const unsigned short* __restrict__ zpb, const float* __restrict__ wsum,
        const float* __restrict__ pw, const float* __restrict__ pb,
        float* __restrict__ out) {
    __shared__ float zsh[HD];
    __shared__ float part[256];
    __shared__ float shb[3];
    beta_from_wsum(wsum, shb);
    int n = blockIdx.x, tid = threadIdx.x;
    float b0 = shb[0], b1 = shb[1], b2 = shb[2];
    const unsigned short* zr = zpb + (size_t)n * (PP * HD);
    int c = tid * 2;
    unsigned u0 = *(const unsigned*)(zr + c);
    unsigned u1 = *(const unsigned*)(zr + HD + c);
    unsigned u2 = *(const unsigned*)(zr + 2 * HD + c);
    zsh[c]     = b0 * bf2f_lo(u0) + b1 * bf2f_lo(u1) + b2 * bf2f_lo(u2);
    zsh[c + 1] = b0 * bf2f_hi(u0) + b1 * bf2f_hi(u1) + b2 * bf2f_hi(u2);
    __syncthreads();
    int o = tid & 63, w = tid >> 6;
    float s = 0.f;
    for (int j = w * 128; j < w * 128 + 128; ++j) s += zsh[j] * pw[j * 64 + o];
    part[tid] = s;
    __syncthreads();
    if (tid < 64)
        out[(size_t)n * 64 + o] =
            part[o] + part[64 + o] + part[128 + o] + part[192 + o] + pb[o];
}

// ---- K6: atten row builder — packed (alpha-pos, dst) pairs, 1 random read/edge ----
__global__ __launch_bounds__(256) void atten_rows(
        const int2* __restrict__ spair, const int* __restrict__ soffs,
        const float* __restrict__ alpha, const float* __restrict__ wsum,
        float* __restrict__ atten) {
    __shared__ float rowbuf[NN];
    __shared__ float shb[3];
    beta_from_wsum(wsum, shb);
    int srow = blockIdx.x, tid = threadIdx.x;
    f32x4 zero = {0.f, 0.f, 0.f, 0.f};
    for (int j = tid; j < NN / 4; j += 256) ((f32x4*)rowbuf)[j] = zero;
    __syncthreads();
    int s0 = soffs[srow], s1 = soffs[srow + 1];
    for (int k = s0 + tid; k < s1; k += 256) {
        int2 pr = spair[k];
        float val = alpha[pr.x] * shb[pr.x >> 18];
        atomicAdd(&rowbuf[pr.y], val);
    }
    __syncthreads();
    float* orow = atten + (size_t)srow * NN;
    for (int j = tid * 4; j < NN; j += 1024) {
        f32x4 v = *(f32x4*)(rowbuf + j);
        __builtin_nontemporal_store(v, (f32x4*)(orow + j));
    }
}

extern "C" void kernel_launch(void* const* d_in, const int* in_sizes, int n_in,
                              void* d_out, int out_size, void* d_ws, size_t ws_size,
                              hipStream_t stream) {
    const float* h    = (const float*)d_in[0];
    const int*   esrc = (const int*)d_in[1];
    const int*   edst = (const int*)d_in[2];
    const float* fc   = (const float*)d_in[3];
    const float* al   = (const float*)d_in[4];
    const float* ar   = (const float*)d_in[5];
    const float* bias = (const float*)d_in[6];
    const float* w1   = (const float*)d_in[7];
    const float* b1   = (const float*)d_in[8];
    const float* w2   = (const float*)d_in[9];
    const float* pw   = (const float*)d_in[10];
    const float* pb   = (const float*)d_in[11];
    float* out   = (float*)d_out;
    float* atten = out + (size_t)NN * OUTF;

    char* ws = (char*)d_ws;
    size_t off = 0;
    auto alloc = [&](size_t bytes) {
        void* p = ws + off;
        off = (off + bytes + 255) & ~(size_t)255;
        return p;
    };
    unsigned short* zpb   = (unsigned short*)alloc(sizeof(short) * (size_t)NN * PP * HD);  // 24 MB
    unsigned short* featb = (unsigned short*)alloc(sizeof(short) * (size_t)PP * NN * HD);  // 24 MB
    unsigned short* hb  = (unsigned short*)alloc(sizeof(short) * (size_t)NN * INF_);       // 4 MB
    unsigned short* fcT = (unsigned short*)alloc(sizeof(short) * (size_t)PP * HD * INF_);  // 768 KB
    float*  el      = (float*)alloc(sizeof(float) * PP * NN * HEADS);
    float*  er      = (float*)alloc(sizeof(float) * PP * NN * HEADS);
    float*  alpha   = (float*)alloc(sizeof(float) * (size_t)PP * NE);       // 3 MB (dst-sorted)
    int*    counts  = (int*)alloc(sizeof(int) * 4 * NN);                    // 128 KB
    float*  wsum    = (float*)alloc(sizeof(float) * 3 * 64);                // right after counts
    int*    offsets = (int*)alloc(sizeof(int) * 4 * (NN + 1));
    int*    cursor  = (int*)alloc(sizeof(int) * 4 * NN);
    int*    ssrc_sorted = (int*)alloc(sizeof(int) * (size_t)PP * NE);       // 3 MB (dst CSR: src vals)
    int2*   spair   = (int2*)alloc(sizeof(int2) * (size_t)PP * NE);         // 6 MB (src CSR: alpha-pos+dst)
    float*  vbuf    = (float*)alloc(sizeof(float) * (HD + 1));

    // zero counts (4 segs) + wsum bins in one memset (contiguous allocs)
    (void)hipMemsetAsync(counts, 0, sizeof(int) * 4 * NN + 1024, stream);

    // casts + global-atomic histograms in one launch
    cast_count<<<2048 + 1536 + 3072, 256, 0, stream>>>(
        h, fc, esrc, edst, hb, fcT, counts);

    // scans (4 segs) + collapsed semantic vector
    scan_vw<<<5, 1024, 0, stream>>>(counts, offsets, cursor, w1, b1, w2, vbuf);

    // CSR scatter: dst CSR (src values) + src CSR (packed alpha-pos+dst)
    scatter_all<<<PP * NE / 256, 256, 0, stream>>>(
        esrc, edst, cursor, ssrc_sorted, spair);

    // features (bf16 out) + fused attention logits
    gemm_feat_mfma<<<dim3(HD / 64, NN / 64, PP), 256, 0, stream>>>(
        hb, fcT, al, ar, featb, el, er);

    // fused edge-softmax + aggregation + elu + semantic-w partials
    fused_attn_rst<<<NN * PP / 4, 256, 0, stream>>>(
        ssrc_sorted, offsets, el, er, featb, bias, vbuf, alpha, zpb, wsum);

    // outputs (beta computed inline from wsum in both kernels)
    final_out<<<NN, 256, 0, stream>>>(zpb, wsum, pw, pb, out);
    atten_rows<<<NN, 256, 0, stream>>>(
        spair, offsets + 3 * (NN + 1), alpha, wsum, atten);
}